// Round 9
// baseline (156.000 us; speedup 1.0000x reference)
//
#include <hip/hip_runtime.h>
#include <math.h>

#define FL 48
#define STP 16  // stats padding stride (floats): one 64B line per counter

__device__ __forceinline__ float sigmoidf(float v) { return 1.0f / (1.0f + expf(-v)); }

// ch for node s: sigmoid( (sum_{j in N(s)} dl[csr[j]]) / max(deg,1) + cb + dr[s] )
__device__ __forceinline__ float ch_node(int s, const int* __restrict__ csr,
                                         const int* __restrict__ off,
                                         const float* __restrict__ dl,
                                         const float* __restrict__ dr, float cb) {
  int j0 = off[s], j1 = off[s + 1];
  float g = 0.0f;
  for (int j = j0; j < j1; ++j) g += dl[csr[j]];
  return sigmoidf(g / fmaxf((float)(j1 - j0), 1.0f) + cb + dr[s]);
}

// ---------------- kernels ----------------

// blocks 0..255: e0 degree+scatter (C_in=1 level).
// blocks 256..258: CSR build (by dst) for graphs e1,e2,e3 entirely in-LDS.
__global__ __launch_bounds__(256) void k_graph(
    const int* __restrict__ e0, const float* __restrict__ ximg,
    float* __restrict__ cnt0, float* __restrict__ aggS0,
    const int* __restrict__ e1, int* __restrict__ off1, int* __restrict__ csr1,
    const int* __restrict__ e2, int* __restrict__ off2, int* __restrict__ csr2,
    const int* __restrict__ e3, int* __restrict__ off3, int* __restrict__ csr3) {
  int blk = blockIdx.x;
  if (blk < 256) {
    int i = blk * 256 + threadIdx.x;
    int d = e0[65536 + i];
    atomicAdd(&cnt0[d], 1.0f);
    atomicAdd(&aggS0[d], ximg[e0[i]]);
    return;
  }
  __shared__ int buf[4096];
  __shared__ int part[256];
  const int* e; int* off; int* csr; int N, E;
  if (blk == 256)      { e = e1; off = off1; csr = csr1; N = 4096; E = 16384; }
  else if (blk == 257) { e = e2; off = off2; csr = csr2; N = 1024; E = 4096; }
  else                 { e = e3; off = off3; csr = csr3; N = 256;  E = 1024; }
  int t = threadIdx.x;
  for (int n = t; n < N; n += 256) buf[n] = 0;
  __syncthreads();
  for (int i = t; i < E; i += 256) atomicAdd(&buf[e[E + i]], 1);  // LDS histogram
  __syncthreads();
  int chunk = N / 256;  // 16 / 4 / 1
  int base = t * chunk;
  int s = 0;
  for (int i = 0; i < chunk; ++i) s += buf[base + i];
  part[t] = s;
  __syncthreads();
  for (int o = 1; o < 256; o <<= 1) {
    int v = (t >= o) ? part[t - o] : 0;
    __syncthreads();
    part[t] += v;
    __syncthreads();
  }
  int run = part[t] - s;  // exclusive prefix of this chunk
  for (int i = 0; i < chunk; ++i) {
    int c = buf[base + i];
    off[base + i] = run;
    buf[base + i] = run;  // becomes the fill cursor
    run += c;
  }
  if (t == 255) off[N] = E;
  __syncthreads();
  for (int i = t; i < E; i += 256) {
    int d = e[E + i];
    int pos = atomicAdd(&buf[d], 1);  // LDS cursor
    csr[pos] = e[i];
  }
}

// sage1 (C_in=1) + relu + pool 128->64 -> xp1; per-node dl2/dr2; per-block att1 stats.
// 1024 blocks x 4 output nodes.
__global__ __launch_bounds__(256) void k_s1(
    const float* __restrict__ ximg, const float* __restrict__ aggS0,
    const float* __restrict__ cnt0,
    const float* __restrict__ Wl, const float* __restrict__ bl,
    const float* __restrict__ Wr,
    const float* __restrict__ cWl, const float* __restrict__ cWr,
    float* __restrict__ y, float* __restrict__ dl, float* __restrict__ dr,
    float* __restrict__ sumP, float* __restrict__ maxP) {
  __shared__ float ldl[4], ldr[4], lsum[FL];
  __shared__ unsigned lmax[FL];
  int t = threadIdx.x;
  if (t < 4) { ldl[t] = 0.0f; ldr[t] = 0.0f; }
  if (t < FL) { lsum[t] = 0.0f; lmax[t] = 0u; }
  __syncthreads();
  if (t < 4 * FL) {
    int q = t / FL, c = t % FL;
    int m = blockIdx.x * 4 + q;  // node on 64x64 grid
    int a = m >> 6, b = m & 63;
    float wl = Wl[c], wr = Wr[c], bb = bl[c];
    float best = -INFINITY;
#pragma unroll
    for (int da = 0; da < 2; ++da)
#pragma unroll
      for (int db = 0; db < 2; ++db) {
        int n = (2 * a + da) * 128 + (2 * b + db);
        float mean = aggS0[n] / fmaxf(cnt0[n], 1.0f);
        best = fmaxf(best, fmaxf(mean * wl + bb + ximg[n] * wr, 0.0f));
      }
    y[m * FL + c] = best;
    atomicAdd(&ldl[q], best * cWl[c]);
    atomicAdd(&ldr[q], best * cWr[c]);
    atomicAdd(&lsum[c], best);
    atomicMax(&lmax[c], __float_as_uint(best));  // post-relu >= 0
  }
  __syncthreads();
  if (t < 4) { int m = blockIdx.x * 4 + t; dl[m] = ldl[t]; dr[m] = ldr[t]; }
  if (t < FL) {
    atomicAdd(&sumP[t * STP], lsum[t]);
    atomicMax((unsigned*)&maxP[t * STP], lmax[t]);
  }
}

// Fused attention+SAGE level: att (from padded stats), per-node ch via CSR dl-gather,
// gated neighbor-mean gather, 48x48 matvec, relu (+pool). Block = 4 output nodes.
// Optionally emits next level's dl/dr and stats.
template <int POOL, int HAS_NEXT>
__global__ __launch_bounds__(256) void k_B(
    const float* __restrict__ x, int N, int H,
    const int* __restrict__ csr, const int* __restrict__ off,
    const float* __restrict__ dl, const float* __restrict__ dr,
    const float* __restrict__ cbl,
    const float* __restrict__ sumP, const float* __restrict__ maxP,
    const float* __restrict__ amW, const float* __restrict__ amb,
    const float* __restrict__ axW, const float* __restrict__ axb,
    const float* __restrict__ Wl, const float* __restrict__ bl,
    const float* __restrict__ Wr,
    float* __restrict__ y,
    float* __restrict__ ndl, float* __restrict__ ndr,
    const float* __restrict__ ncWl, const float* __restrict__ ncWr,
    float* __restrict__ nsum, float* __restrict__ nmax) {
  const int NS = POOL ? 16 : 4;
  __shared__ float sWl[FL * FL], sWr[FL * FL], sAtt[FL];
  __shared__ float smean[16][FL], sx[16][FL];
  __shared__ float chE[16][32], chS[16], rcS[16];
  __shared__ float ldl[4], ldr[4], lsum[FL];
  __shared__ unsigned lmax[FL];
  int t = threadIdx.x;
  int Ho = H >> 1;
  float cb = cbl[0];

  auto node_of = [&](int k) -> int {
    int m = blockIdx.x * 4 + (POOL ? (k >> 2) : k);
    if (POOL) {
      int a = m / Ho, b = m % Ho;
      return (2 * a + ((k >> 1) & 1)) * H + (2 * b + (k & 1));
    }
    return m;
  };

  if (t < FL) {  // att vector (redundant per block; weights L2-hot)
    float s = amb[t] + axb[t];
    float invN = 1.0f / (float)N;
    for (int ci = 0; ci < FL; ++ci)
      s += (sumP[ci * STP] * invN) * amW[ci * FL + t] + maxP[ci * STP] * axW[ci * FL + t];
    sAtt[t] = sigmoidf(s);
  }
  for (int i = t; i < FL * FL; i += 256) { sWl[i] = Wl[i]; sWr[i] = Wr[i]; }
  if (HAS_NEXT) {
    if (t < 4) { ldl[t] = 0.0f; ldr[t] = 0.0f; }
    if (t < FL) { lsum[t] = 0.0f; lmax[t] = 0u; }
  }
  if (t < NS) {  // subnode gates + reciprocal degree
    int n = node_of(t);
    chS[t] = ch_node(n, csr, off, dl, dr, cb);
    rcS[t] = 1.0f / fmaxf((float)(off[n + 1] - off[n]), 1.0f);
  }
  for (int idx = t; idx < NS * 32; idx += 256) {  // neighbor gates per edge slot
    int k = idx >> 5, r = idx & 31;
    int n = node_of(k);
    int j = off[n] + r;
    if (j < off[n + 1]) chE[k][r] = ch_node(csr[j], csr, off, dl, dr, cb);
  }
  __syncthreads();

  // gather: (subnode k, channel ci); consecutive ci -> coalesced row reads
  for (int idx = t; idx < NS * FL; idx += 256) {
    int k = idx / FL, ci = idx % FL;
    int n = node_of(k);
    int j0 = off[n], j1 = off[n + 1];
    float g1 = 1.0f + sAtt[ci];
    float acc = 0.0f;
    for (int j = j0; j < j1; ++j) {
      int s = csr[j];
      int r = j - j0;
      float chv = (r < 32) ? chE[k][r] : ch_node(s, csr, off, dl, dr, cb);
      acc += x[s * FL + ci] * (g1 + chv);
    }
    smean[k][ci] = acc * rcS[k];
    sx[k][ci] = x[n * FL + ci] * (g1 + chS[k]);
  }
  __syncthreads();

  // output: (node q, channel c); smean reads broadcast within wave
  if (t < 4 * FL) {
    int q = t / FL, c = t % FL;
    int m = blockIdx.x * 4 + q;
    float best = -INFINITY;
#pragma unroll
    for (int sub = 0; sub < (POOL ? 4 : 1); ++sub) {
      int k = POOL ? q * 4 + sub : q;
      float s = bl[c];
      for (int ci = 0; ci < FL; ++ci)
        s += smean[k][ci] * sWl[ci * FL + c] + sx[k][ci] * sWr[ci * FL + c];
      best = fmaxf(best, fmaxf(s, 0.0f));
    }
    y[m * FL + c] = best;
    if (HAS_NEXT) {
      atomicAdd(&ldl[q], best * ncWl[c]);
      atomicAdd(&ldr[q], best * ncWr[c]);
      atomicAdd(&lsum[c], best);
      atomicMax(&lmax[c], __float_as_uint(best));
    }
  }
  if (HAS_NEXT) {
    __syncthreads();
    if (t < 4) { int m = blockIdx.x * 4 + t; ndl[m] = ldl[t]; ndr[m] = ldr[t]; }
    if (t < FL) {
      atomicAdd(&nsum[t * STP], lsum[t]);
      atomicMax((unsigned*)&nmax[t * STP], lmax[t]);
    }
  }
}

// FC1 split-K: block b covers k in [b*96, b*96+96); k = c*256+n -> x4[n*48+c]
__global__ __launch_bounds__(256) void k_fc1(const float* __restrict__ x4,
                                             const float* __restrict__ W,
                                             float* __restrict__ accP) {
  __shared__ float xin[96];
  int k0 = blockIdx.x * 96;
  int t = threadIdx.x;
  if (t < 96) {
    int k = k0 + t;
    xin[t] = x4[(k & 255) * FL + (k >> 8)];
  }
  __syncthreads();
  float a = 0.0f;
  for (int i = 0; i < 96; ++i) a += xin[i] * W[(size_t)(k0 + i) * 256 + t];
  atomicAdd(&accP[t * STP], a);
}

// fc1 bias+relu, fc2, log_softmax
__global__ void k_final(const float* __restrict__ accP, const float* __restrict__ b1,
                        const float* __restrict__ W2, const float* __restrict__ b2,
                        float* __restrict__ out) {
  __shared__ float av[256];
  __shared__ float logits[10];
  int t = threadIdx.x;
  av[t] = fmaxf(accP[t * STP] + b1[t], 0.0f);
  __syncthreads();
  if (t < 10) {
    float s = b2[t];
    for (int o = 0; o < 256; ++o) s += av[o] * W2[o * 10 + t];
    logits[t] = s;
  }
  __syncthreads();
  if (t == 0) {
    float m = logits[0];
    for (int j = 1; j < 10; ++j) m = fmaxf(m, logits[j]);
    float s = 0.0f;
    for (int j = 0; j < 10; ++j) s += expf(logits[j] - m);
    float ls = logf(s);
    for (int j = 0; j < 10; ++j) out[j] = logits[j] - m - ls;
  }
}

// ---------------- launch ----------------

static inline int cdiv(int a, int b) { return (a + b - 1) / b; }

extern "C" void kernel_launch(void* const* d_in, const int* in_sizes, int n_in,
                              void* d_out, int out_size, void* d_ws, size_t ws_size,
                              hipStream_t stream) {
  const float* ximg = (const float*)d_in[0];
  const int* e0 = (const int*)d_in[1];
  const int* e1 = (const int*)d_in[2];
  const int* e2 = (const int*)d_in[3];
  const int* e3 = (const int*)d_in[4];
  const float* g1Wl = (const float*)d_in[6];
  const float* g1bl = (const float*)d_in[7];
  const float* g1Wr = (const float*)d_in[8];
  const float* gWl[3] = {(const float*)d_in[9], (const float*)d_in[12], (const float*)d_in[15]};
  const float* gbl[3] = {(const float*)d_in[10], (const float*)d_in[13], (const float*)d_in[16]};
  const float* gWr[3] = {(const float*)d_in[11], (const float*)d_in[14], (const float*)d_in[17]};
  const float* amW[3]; const float* amb[3]; const float* axW[3]; const float* axb[3];
  const float* cWl[3]; const float* cbl[3]; const float* cWr[3];
  for (int i = 0; i < 3; ++i) {
    int base = 18 + i * 7;
    amW[i] = (const float*)d_in[base + 0];
    amb[i] = (const float*)d_in[base + 1];
    axW[i] = (const float*)d_in[base + 2];
    axb[i] = (const float*)d_in[base + 3];
    cWl[i] = (const float*)d_in[base + 4];
    cbl[i] = (const float*)d_in[base + 5];
    cWr[i] = (const float*)d_in[base + 6];
  }
  const float* fc1W = (const float*)d_in[46];
  const float* fc1b = (const float*)d_in[47];
  const float* fc2W = (const float*)d_in[48];
  const float* fc2b = (const float*)d_in[49];
  float* out = (float*)d_out;

  const int N0 = 16384, N1 = 4096, N2 = 1024, N3 = 256;
  const int E1 = 16384, E2 = 4096, E3 = 1024;

  // byte allocator, 4KB-aligned buffers; [zeroed region][rest]
  char* basep = (char*)d_ws;
  size_t off = 0;
  auto alloc = [&](size_t bytes) -> void* {
    void* q = basep + off;
    off += (bytes + 4095) & ~(size_t)4095;
    return q;
  };
  // ---- zeroed region ----
  float* cnt0 = (float*)alloc(N0 * 4);
  float* aggS0 = (float*)alloc(N0 * 4);
  float* fc1acc = (float*)alloc(256 * STP * 4);
  float* sum1 = (float*)alloc(FL * STP * 4); float* max1 = (float*)alloc(FL * STP * 4);
  float* sum2 = (float*)alloc(FL * STP * 4); float* max2 = (float*)alloc(FL * STP * 4);
  float* sum3 = (float*)alloc(FL * STP * 4); float* max3 = (float*)alloc(FL * STP * 4);
  size_t zbytes = off;
  // ---- rest ----
  int* off1 = (int*)alloc((N1 + 1) * 4);
  int* off2 = (int*)alloc((N2 + 1) * 4);
  int* off3 = (int*)alloc((N3 + 1) * 4);
  int* csr1 = (int*)alloc(E1 * 4);
  int* csr2 = (int*)alloc(E2 * 4);
  int* csr3 = (int*)alloc(E3 * 4);
  float* dl2 = (float*)alloc(N1 * 4); float* dr2 = (float*)alloc(N1 * 4);
  float* dl3 = (float*)alloc(N2 * 4); float* dr3 = (float*)alloc(N2 * 4);
  float* dl4 = (float*)alloc(N3 * 4); float* dr4 = (float*)alloc(N3 * 4);
  float* xp1 = (float*)alloc(N1 * FL * 4);
  float* xp2 = (float*)alloc(N2 * FL * 4);
  float* xp3 = (float*)alloc(N3 * FL * 4);
  float* x4 = (float*)alloc(N3 * FL * 4);

  // 1: zero accumulators
  hipMemsetAsync(d_ws, 0, zbytes, stream);
  // 2: e0 scatter + CSR build (graphs 1-3)
  k_graph<<<259, 256, 0, stream>>>(e0, ximg, cnt0, aggS0,
                                   e1, off1, csr1, e2, off2, csr2, e3, off3, csr3);
  // 3: sage1+pool -> xp1 (+dl2/dr2, att1 stats)
  k_s1<<<N1 / 4, 256, 0, stream>>>(ximg, aggS0, cnt0, g1Wl, g1bl, g1Wr,
                                   cWl[0], cWr[0], xp1, dl2, dr2, sum1, max1);
  // 4-6: fused att+SAGE levels
  k_B<1, 1><<<N2 / 4, 256, 0, stream>>>(xp1, N1, 64, csr1, off1, dl2, dr2, cbl[0],
                                        sum1, max1, amW[0], amb[0], axW[0], axb[0],
                                        gWl[0], gbl[0], gWr[0], xp2,
                                        dl3, dr3, cWl[1], cWr[1], sum2, max2);
  k_B<1, 1><<<N3 / 4, 256, 0, stream>>>(xp2, N2, 32, csr2, off2, dl3, dr3, cbl[1],
                                        sum2, max2, amW[1], amb[1], axW[1], axb[1],
                                        gWl[1], gbl[1], gWr[1], xp3,
                                        dl4, dr4, cWl[2], cWr[2], sum3, max3);
  k_B<0, 0><<<N3 / 4, 256, 0, stream>>>(xp3, N3, 16, csr3, off3, dl4, dr4, cbl[2],
                                        sum3, max3, amW[2], amb[2], axW[2], axb[2],
                                        gWl[2], gbl[2], gWr[2], x4,
                                        (float*)nullptr, (float*)nullptr,
                                        (const float*)nullptr, (const float*)nullptr,
                                        (float*)nullptr, (float*)nullptr);
  // 7: FC1 split-K
  k_fc1<<<128, 256, 0, stream>>>(x4, fc1W, fc1acc);
  // 8: head
  k_final<<<1, 256, 0, stream>>>(fc1acc, fc1b, fc2W, fc2b, out);

  (void)in_sizes; (void)n_in; (void)out_size; (void)ws_size;
}

// Round 10
// 128.090 us; speedup vs baseline: 1.2179x; 1.2179x over previous
//
#include <hip/hip_runtime.h>
#include <math.h>

#define FL 48
#define STP 16   // stats padding stride (floats): one 64B line per counter
#define CAP 64   // bucket capacity per node (avg degree 4; Poisson tail ~0)

__device__ __forceinline__ float sigmoidf(float v) { return 1.0f / (1.0f + expf(-v)); }

__device__ __forceinline__ float gld(const float* p) {
  return __hip_atomic_load(p, __ATOMIC_RELAXED, __HIP_MEMORY_SCOPE_AGENT);
}

// ch for node s: sigmoid( (sum_{j in N(s)} dl[nb]) / max(deg,1) + cb + dr[s] )
__device__ __forceinline__ float ch_node(int s, const int* __restrict__ bkt,
                                         const int* __restrict__ cnt,
                                         const float* __restrict__ dl,
                                         const float* __restrict__ dr, float cb) {
  int deg = cnt[s];
  float g = 0.0f;
  for (int j = 0; j < deg; ++j) g += dl[bkt[(s << 6) + j]];
  return sigmoidf(g / fmaxf((float)deg, 1.0f) + cb + dr[s]);
}

// ---------------- kernels ----------------

// one pass over all 87040 edges: e0 degree+scalar scatter; e1/e2/e3 bucket-CSR fill.
__global__ __launch_bounds__(256) void k_graph(
    const int* __restrict__ e0, const float* __restrict__ ximg,
    float* __restrict__ cnt0, float* __restrict__ aggS0,
    const int* __restrict__ e1, int* __restrict__ cnt1, int* __restrict__ b1,
    const int* __restrict__ e2, int* __restrict__ cnt2, int* __restrict__ b2,
    const int* __restrict__ e3, int* __restrict__ cnt3, int* __restrict__ b3) {
  int g = blockIdx.x * 256 + threadIdx.x;
  if (g < 65536) {
    int d = e0[65536 + g];
    atomicAdd(&cnt0[d], 1.0f);
    atomicAdd(&aggS0[d], ximg[e0[g]]);
  } else if (g < 81920) {
    int i = g - 65536;
    int d = e1[16384 + i];
    int pos = atomicAdd(&cnt1[d], 1);
    if (pos < CAP) b1[(d << 6) + pos] = e1[i];
  } else if (g < 86016) {
    int i = g - 81920;
    int d = e2[4096 + i];
    int pos = atomicAdd(&cnt2[d], 1);
    if (pos < CAP) b2[(d << 6) + pos] = e2[i];
  } else if (g < 87040) {
    int i = g - 86016;
    int d = e3[1024 + i];
    int pos = atomicAdd(&cnt3[d], 1);
    if (pos < CAP) b3[(d << 6) + pos] = e3[i];
  }
}

// sage1 (C_in=1) + relu + pool 128->64 -> xp1; per-node dl2/dr2; per-block att1 stats.
__global__ __launch_bounds__(256) void k_s1(
    const float* __restrict__ ximg, const float* __restrict__ aggS0,
    const float* __restrict__ cnt0,
    const float* __restrict__ Wl, const float* __restrict__ bl,
    const float* __restrict__ Wr,
    const float* __restrict__ cWl, const float* __restrict__ cWr,
    float* __restrict__ y, float* __restrict__ dl, float* __restrict__ dr,
    float* __restrict__ sumP, float* __restrict__ maxP) {
  __shared__ float ldl[4], ldr[4], lsum[FL];
  __shared__ unsigned lmax[FL];
  int t = threadIdx.x;
  if (t < 4) { ldl[t] = 0.0f; ldr[t] = 0.0f; }
  if (t < FL) { lsum[t] = 0.0f; lmax[t] = 0u; }
  __syncthreads();
  if (t < 4 * FL) {
    int q = t / FL, c = t % FL;
    int m = blockIdx.x * 4 + q;  // node on 64x64 grid
    int a = m >> 6, b = m & 63;
    float wl = Wl[c], wr = Wr[c], bb = bl[c];
    float best = -INFINITY;
#pragma unroll
    for (int da = 0; da < 2; ++da)
#pragma unroll
      for (int db = 0; db < 2; ++db) {
        int n = (2 * a + da) * 128 + (2 * b + db);
        float mean = aggS0[n] / fmaxf(cnt0[n], 1.0f);
        best = fmaxf(best, fmaxf(mean * wl + bb + ximg[n] * wr, 0.0f));
      }
    y[m * FL + c] = best;
    atomicAdd(&ldl[q], best * cWl[c]);
    atomicAdd(&ldr[q], best * cWr[c]);
    atomicAdd(&lsum[c], best);
    atomicMax(&lmax[c], __float_as_uint(best));  // post-relu >= 0
  }
  __syncthreads();
  if (t < 4) { int m = blockIdx.x * 4 + t; dl[m] = ldl[t]; dr[m] = ldr[t]; }
  if (t < FL) {
    atomicAdd(&sumP[t * STP], lsum[t]);
    atomicMax((unsigned*)&maxP[t * STP], lmax[t]);
  }
}

// Fused attention+SAGE level via bucket-CSR. Block = 4 output nodes.
template <int POOL, int HAS_NEXT>
__global__ __launch_bounds__(256) void k_B(
    const float* __restrict__ x, int N, int H,
    const int* __restrict__ bkt, const int* __restrict__ cnt,
    const float* __restrict__ dl, const float* __restrict__ dr,
    const float* __restrict__ cbl,
    const float* __restrict__ sumP, const float* __restrict__ maxP,
    const float* __restrict__ amW, const float* __restrict__ amb,
    const float* __restrict__ axW, const float* __restrict__ axb,
    const float* __restrict__ Wl, const float* __restrict__ bl,
    const float* __restrict__ Wr,
    float* __restrict__ y,
    float* __restrict__ ndl, float* __restrict__ ndr,
    const float* __restrict__ ncWl, const float* __restrict__ ncWr,
    float* __restrict__ nsum, float* __restrict__ nmax) {
  const int NS = POOL ? 16 : 4;
  __shared__ float sWl[FL * FL], sWr[FL * FL], sAtt[FL];
  __shared__ float smean[16][FL], sx[16][FL];
  __shared__ float chE[16][32], chS[16], rcS[16];
  __shared__ float ldl[4], ldr[4], lsum[FL];
  __shared__ unsigned lmax[FL];
  int t = threadIdx.x;
  int Ho = H >> 1;
  float cb = cbl[0];

  auto node_of = [&](int k) -> int {
    int m = blockIdx.x * 4 + (POOL ? (k >> 2) : k);
    if (POOL) {
      int a = m / Ho, b = m % Ho;
      return (2 * a + ((k >> 1) & 1)) * H + (2 * b + (k & 1));
    }
    return m;
  };

  if (t < FL) {  // att vector (redundant per block; weights L2-hot)
    float s = amb[t] + axb[t];
    float invN = 1.0f / (float)N;
    for (int ci = 0; ci < FL; ++ci)
      s += (sumP[ci * STP] * invN) * amW[ci * FL + t] + maxP[ci * STP] * axW[ci * FL + t];
    sAtt[t] = sigmoidf(s);
  }
  for (int i = t; i < FL * FL; i += 256) { sWl[i] = Wl[i]; sWr[i] = Wr[i]; }
  if (HAS_NEXT) {
    if (t < 4) { ldl[t] = 0.0f; ldr[t] = 0.0f; }
    if (t < FL) { lsum[t] = 0.0f; lmax[t] = 0u; }
  }
  if (t < NS) {  // subnode gates + reciprocal degree
    int n = node_of(t);
    chS[t] = ch_node(n, bkt, cnt, dl, dr, cb);
    rcS[t] = 1.0f / fmaxf((float)cnt[n], 1.0f);
  }
  for (int idx = t; idx < NS * 32; idx += 256) {  // neighbor gates per edge slot
    int k = idx >> 5, r = idx & 31;
    int n = node_of(k);
    if (r < cnt[n]) chE[k][r] = ch_node(bkt[(n << 6) + r], bkt, cnt, dl, dr, cb);
  }
  __syncthreads();

  // gather: (subnode k, channel ci); consecutive ci -> coalesced row reads
  for (int idx = t; idx < NS * FL; idx += 256) {
    int k = idx / FL, ci = idx % FL;
    int n = node_of(k);
    int deg = cnt[n];
    float g1 = 1.0f + sAtt[ci];
    float acc = 0.0f;
    for (int j = 0; j < deg; ++j) {
      int s = bkt[(n << 6) + j];
      float chv = (j < 32) ? chE[k][j] : ch_node(s, bkt, cnt, dl, dr, cb);
      acc += x[s * FL + ci] * (g1 + chv);
    }
    smean[k][ci] = acc * rcS[k];
    sx[k][ci] = x[n * FL + ci] * (g1 + chS[k]);
  }
  __syncthreads();

  // output: (node q, channel c)
  if (t < 4 * FL) {
    int q = t / FL, c = t % FL;
    int m = blockIdx.x * 4 + q;
    float best = -INFINITY;
#pragma unroll
    for (int sub = 0; sub < (POOL ? 4 : 1); ++sub) {
      int k = POOL ? q * 4 + sub : q;
      float s = bl[c];
      for (int ci = 0; ci < FL; ++ci)
        s += smean[k][ci] * sWl[ci * FL + c] + sx[k][ci] * sWr[ci * FL + c];
      best = fmaxf(best, fmaxf(s, 0.0f));
    }
    y[m * FL + c] = best;
    if (HAS_NEXT) {
      atomicAdd(&ldl[q], best * ncWl[c]);
      atomicAdd(&ldr[q], best * ncWr[c]);
      atomicAdd(&lsum[c], best);
      atomicMax(&lmax[c], __float_as_uint(best));
    }
  }
  if (HAS_NEXT) {
    __syncthreads();
    if (t < 4) { int m = blockIdx.x * 4 + t; ndl[m] = ldl[t]; ndr[m] = ldr[t]; }
    if (t < FL) {
      atomicAdd(&nsum[t * STP], lsum[t]);
      atomicMax((unsigned*)&nmax[t * STP], lmax[t]);
    }
  }
}

// FC1 split-K + (last block) bias/relu/fc2/log_softmax.
// 128 blocks; block b covers k in [b*96, b*96+96); k = c*256+n -> x4[n*48+c]
__global__ __launch_bounds__(256) void k_head(
    const float* __restrict__ x4, const float* __restrict__ W,
    const float* __restrict__ b1, const float* __restrict__ W2,
    const float* __restrict__ b2, float* __restrict__ accP,
    unsigned* __restrict__ done, float* __restrict__ out) {
  __shared__ float xin[96];
  __shared__ unsigned rank;
  int k0 = blockIdx.x * 96;
  int t = threadIdx.x;
  if (t < 96) {
    int k = k0 + t;
    xin[t] = x4[(k & 255) * FL + (k >> 8)];
  }
  __syncthreads();
  float a = 0.0f;
  for (int i = 0; i < 96; ++i) a += xin[i] * W[(size_t)(k0 + i) * 256 + t];
  atomicAdd(&accP[t * STP], a);
  __syncthreads();
  if (t == 0)
    rank = __hip_atomic_fetch_add(done, 1u, __ATOMIC_ACQ_REL, __HIP_MEMORY_SCOPE_AGENT);
  __syncthreads();
  if (rank == 127) {  // last block: all 128 adds are visible (release/acquire chain)
    __shared__ float av[256];
    __shared__ float logits[10];
    av[t] = fmaxf(gld(&accP[t * STP]) + b1[t], 0.0f);
    __syncthreads();
    if (t < 10) {
      float s = b2[t];
      for (int o = 0; o < 256; ++o) s += av[o] * W2[o * 10 + t];
      logits[t] = s;
    }
    __syncthreads();
    if (t == 0) {
      float m = logits[0];
      for (int j = 1; j < 10; ++j) m = fmaxf(m, logits[j]);
      float s = 0.0f;
      for (int j = 0; j < 10; ++j) s += expf(logits[j] - m);
      float ls = logf(s);
      for (int j = 0; j < 10; ++j) out[j] = logits[j] - m - ls;
    }
  }
}

// ---------------- launch ----------------

static inline int cdiv(int a, int b) { return (a + b - 1) / b; }

extern "C" void kernel_launch(void* const* d_in, const int* in_sizes, int n_in,
                              void* d_out, int out_size, void* d_ws, size_t ws_size,
                              hipStream_t stream) {
  const float* ximg = (const float*)d_in[0];
  const int* e0 = (const int*)d_in[1];
  const int* e1 = (const int*)d_in[2];
  const int* e2 = (const int*)d_in[3];
  const int* e3 = (const int*)d_in[4];
  const float* g1Wl = (const float*)d_in[6];
  const float* g1bl = (const float*)d_in[7];
  const float* g1Wr = (const float*)d_in[8];
  const float* gWl[3] = {(const float*)d_in[9], (const float*)d_in[12], (const float*)d_in[15]};
  const float* gbl[3] = {(const float*)d_in[10], (const float*)d_in[13], (const float*)d_in[16]};
  const float* gWr[3] = {(const float*)d_in[11], (const float*)d_in[14], (const float*)d_in[17]};
  const float* amW[3]; const float* amb[3]; const float* axW[3]; const float* axb[3];
  const float* cWl[3]; const float* cbl[3]; const float* cWr[3];
  for (int i = 0; i < 3; ++i) {
    int base = 18 + i * 7;
    amW[i] = (const float*)d_in[base + 0];
    amb[i] = (const float*)d_in[base + 1];
    axW[i] = (const float*)d_in[base + 2];
    axb[i] = (const float*)d_in[base + 3];
    cWl[i] = (const float*)d_in[base + 4];
    cbl[i] = (const float*)d_in[base + 5];
    cWr[i] = (const float*)d_in[base + 6];
  }
  const float* fc1W = (const float*)d_in[46];
  const float* fc1b = (const float*)d_in[47];
  const float* fc2W = (const float*)d_in[48];
  const float* fc2b = (const float*)d_in[49];
  float* out = (float*)d_out;

  const int N0 = 16384, N1 = 4096, N2 = 1024, N3 = 256;

  // byte allocator, 4KB-aligned buffers; [zeroed region][rest]
  char* basep = (char*)d_ws;
  size_t off = 0;
  auto alloc = [&](size_t bytes) -> void* {
    void* q = basep + off;
    off += (bytes + 4095) & ~(size_t)4095;
    return q;
  };
  // ---- zeroed region ----
  float* cnt0 = (float*)alloc(N0 * 4);
  float* aggS0 = (float*)alloc(N0 * 4);
  int* cnt1 = (int*)alloc(N1 * 4);
  int* cnt2 = (int*)alloc(N2 * 4);
  int* cnt3 = (int*)alloc(N3 * 4);
  float* fc1acc = (float*)alloc(256 * STP * 4);
  unsigned* done = (unsigned*)alloc(64);
  float* sum1 = (float*)alloc(FL * STP * 4); float* max1 = (float*)alloc(FL * STP * 4);
  float* sum2 = (float*)alloc(FL * STP * 4); float* max2 = (float*)alloc(FL * STP * 4);
  float* sum3 = (float*)alloc(FL * STP * 4); float* max3 = (float*)alloc(FL * STP * 4);
  size_t zbytes = off;
  // ---- rest ----
  int* b1 = (int*)alloc(N1 * CAP * 4);
  int* b2 = (int*)alloc(N2 * CAP * 4);
  int* b3 = (int*)alloc(N3 * CAP * 4);
  float* dl2 = (float*)alloc(N1 * 4); float* dr2 = (float*)alloc(N1 * 4);
  float* dl3 = (float*)alloc(N2 * 4); float* dr3 = (float*)alloc(N2 * 4);
  float* dl4 = (float*)alloc(N3 * 4); float* dr4 = (float*)alloc(N3 * 4);
  float* xp1 = (float*)alloc(N1 * FL * 4);
  float* xp2 = (float*)alloc(N2 * FL * 4);
  float* xp3 = (float*)alloc(N3 * FL * 4);
  float* x4 = (float*)alloc(N3 * FL * 4);

  // 1: zero accumulators + cursors + done flag
  hipMemsetAsync(d_ws, 0, zbytes, stream);
  // 2: all-edge pass: e0 scatter + bucket-CSR builds
  k_graph<<<cdiv(87040, 256), 256, 0, stream>>>(e0, ximg, cnt0, aggS0,
                                                e1, cnt1, b1, e2, cnt2, b2, e3, cnt3, b3);
  // 3: sage1+pool -> xp1 (+dl2/dr2, att1 stats)
  k_s1<<<N1 / 4, 256, 0, stream>>>(ximg, aggS0, cnt0, g1Wl, g1bl, g1Wr,
                                   cWl[0], cWr[0], xp1, dl2, dr2, sum1, max1);
  // 4-6: fused att+SAGE levels
  k_B<1, 1><<<N2 / 4, 256, 0, stream>>>(xp1, N1, 64, b1, cnt1, dl2, dr2, cbl[0],
                                        sum1, max1, amW[0], amb[0], axW[0], axb[0],
                                        gWl[0], gbl[0], gWr[0], xp2,
                                        dl3, dr3, cWl[1], cWr[1], sum2, max2);
  k_B<1, 1><<<N3 / 4, 256, 0, stream>>>(xp2, N2, 32, b2, cnt2, dl3, dr3, cbl[1],
                                        sum2, max2, amW[1], amb[1], axW[1], axb[1],
                                        gWl[1], gbl[1], gWr[1], xp3,
                                        dl4, dr4, cWl[2], cWr[2], sum3, max3);
  k_B<0, 0><<<N3 / 4, 256, 0, stream>>>(xp3, N3, 16, b3, cnt3, dl4, dr4, cbl[2],
                                        sum3, max3, amW[2], amb[2], axW[2], axb[2],
                                        gWl[2], gbl[2], gWr[2], x4,
                                        (float*)nullptr, (float*)nullptr,
                                        (const float*)nullptr, (const float*)nullptr,
                                        (float*)nullptr, (float*)nullptr);
  // 7: FC1 split-K + head (last-block finish)
  k_head<<<128, 256, 0, stream>>>(x4, fc1W, fc1b, fc2W, fc2b, fc1acc, done, out);

  (void)in_sizes; (void)n_in; (void)out_size; (void)ws_size;
}